// Round 9
// baseline (381.461 us; speedup 1.0000x reference)
//
#include <hip/hip_runtime.h>
#include <hip/hip_fp16.h>

typedef _Float16 f16x8 __attribute__((ext_vector_type(8)));
typedef float f32x4 __attribute__((ext_vector_type(4)));

// ---------------- fp16 helpers ----------------
union H2I { int i; __half2 h; };
static __device__ inline float2 i2f2(int v) {
    H2I u; u.i = v; return __half22float2(u.h);
}
static __device__ inline int f2i2(float a, float b) {
    H2I u; u.h = __floats2half2_rn(a, b); return u.i;
}
static __device__ inline float hbits2f(unsigned int b) {
    union { unsigned short s; __half h; } u;
    u.s = (unsigned short)b;
    return __half2float(u.h);
}

// ---------------- CSR build ----------------

__global__ __launch_bounds__(256) void count_rank_kernel(const int* __restrict__ col,
                                                         int* __restrict__ cnt,
                                                         unsigned short* __restrict__ rank,
                                                         int E) {
    int e = blockIdx.x * 256 + threadIdx.x;
    if (e < E) rank[e] = (unsigned short)atomicAdd(&cnt[col[e]], 1);
}

__global__ __launch_bounds__(256) void scan_block_kernel(const int* __restrict__ cnt,
                                                         int* __restrict__ off,
                                                         int* __restrict__ bsum, int n) {
    const int gid = blockIdx.x * 256 + threadIdx.x;
    const int v = (gid < n) ? cnt[gid] : 0;
    const int lane = threadIdx.x & 63, w = threadIdx.x >> 6;
    int x = v;
#pragma unroll
    for (int d = 1; d < 64; d <<= 1) {
        int t = __shfl_up(x, d);
        if (lane >= d) x += t;
    }
    __shared__ int wt[4];
    if (lane == 63) wt[w] = x;
    __syncthreads();
    int base = 0;
#pragma unroll
    for (int i = 0; i < 3; ++i)
        if (i < w) base += wt[i];
    const int incl = base + x;
    if (gid < n) off[gid] = incl - v;
    if (threadIdx.x == 255) bsum[blockIdx.x] = incl;
}

// Merged: each block computes its own bsum prefix (nb small), applies, sets off[n].
__global__ __launch_bounds__(256) void scan_apply_kernel(int* __restrict__ off,
                                                         const int* __restrict__ bsum,
                                                         int n, int E) {
    __shared__ int sbase;
    const int tid = threadIdx.x;
    if (tid < 64) {
        int s = 0;
        for (int i = tid; i < blockIdx.x; i += 64) s += bsum[i];
#pragma unroll
        for (int d = 1; d < 64; d <<= 1) s += __shfl_xor(s, d);
        if (tid == 0) sbase = s;
    }
    __syncthreads();
    const int gid = blockIdx.x * 256 + tid;
    if (gid < n) off[gid] += sbase;
    if (gid == n) off[n] = E;
}

// Fused prep: dinv (N), x->xcat fp16 (2N), packB for 4 layers (512 + 3*2048).
__global__ __launch_bounds__(256) void prep_kernel(const int* __restrict__ cnt,
                                                   float* __restrict__ dinv,
                                                   const float* __restrict__ x,
                                                   __half* __restrict__ xcat,
                                                   const float* __restrict__ W0,
                                                   const float* __restrict__ W1,
                                                   const float* __restrict__ W2,
                                                   const float* __restrict__ W3,
                                                   __half* __restrict__ Bp0,
                                                   __half* __restrict__ Bp1,
                                                   __half* __restrict__ Bp2,
                                                   __half* __restrict__ Bp3, int N) {
    int t = blockIdx.x * 256 + threadIdx.x;
    if (t < N) {
        const int c = cnt[t];
        dinv[t] = (c > 0) ? 1.0f / sqrtf((float)c) : 0.0f;
        return;
    }
    t -= N;
    if (t < 2 * N) {
        const int n = t >> 1, q = t & 1;
        const float4 v0 = ((const float4*)x)[n * 4 + q * 2 + 0];
        const float4 v1 = ((const float4*)x)[n * 4 + q * 2 + 1];
        int4 o;
        o.x = f2i2(v0.x, v0.y);
        o.y = f2i2(v0.z, v0.w);
        o.z = f2i2(v1.x, v1.y);
        o.w = f2i2(v1.z, v1.w);
        ((int4*)xcat)[n * 8 + q] = o;
        return;
    }
    t -= 2 * N;
    const float* W;
    __half* Bp;
    if (t < 512) {
        W = W0; Bp = Bp0;
    } else if (t < 512 + 2048) {
        W = W1; Bp = Bp1; t -= 512;
    } else if (t < 512 + 2 * 2048) {
        W = W2; Bp = Bp2; t -= 512 + 2048;
    } else if (t < 512 + 3 * 2048) {
        W = W3; Bp = Bp3; t -= 512 + 2 * 2048;
    } else {
        return;
    }
    const int kk = t >> 8;
    const int nt = (t >> 6) & 3;
    const int l = t & 63;
    const int m = l & 15, kg = l >> 4;
    const int col = nt * 16 + m;
    __half tmp[8];
#pragma unroll
    for (int j = 0; j < 8; ++j) {
        const int k = kk * 32 + kg * 8 + j;
        tmp[j] = __float2half(W[k * 64 + col]);
    }
    ((int4*)Bp)[t] = *(int4*)tmp;
}

// Scatter edge -> packed record: src (17 bits) | norm (15-bit fp16, sign+LSB dropped).
__global__ __launch_bounds__(256) void scatter_kernel(const int* __restrict__ row,
                                                      const int* __restrict__ col,
                                                      const int* __restrict__ off,
                                                      const unsigned short* __restrict__ rank,
                                                      const float* __restrict__ dinv,
                                                      unsigned int* __restrict__ recs, int E) {
    int e = blockIdx.x * 256 + threadIdx.x;
    if (e >= E) return;
    const int r = row[e], c = col[e];
    const int pos = off[c] + (int)rank[e];
    const unsigned int nb = (unsigned int)__half_as_ushort(__float2half_rn(dinv[r] * dinv[c]));
    recs[pos] = ((unsigned int)r << 15) | (nb >> 1);
}

// ---------------- wave-per-node gather: out-slice = A_norm * in-slice ----------------
// GS = ES*Q lanes per node (NPW = 64/GS nodes per wave). ES edge slots in flight;
// Q int4 chunks (8 halfs each) per row. shfl_xor tree-reduce across edge slots.
// Balanced: wave time ~ ceil(own degree / ES), no max-of-many-nodes divergence.

template <int ES, int Q, int S4>
__global__ __launch_bounds__(256) void gatherw_kernel(const int* __restrict__ off,
                                                      const unsigned int* __restrict__ recs,
                                                      const __half* __restrict__ hin,
                                                      __half* __restrict__ hout, int nNodes) {
    constexpr int GS = ES * Q;
    constexpr int NPW = 64 / GS;
    const int wid = (blockIdx.x * 256 + threadIdx.x) >> 6;
    const int lane = threadIdx.x & 63;
    const int n = wid * NPW + lane / GS;
    if (n >= nNodes) return;
    const int gl = lane % GS;
    const int es = gl / Q;
    const int q = gl % Q;
    const int4* __restrict__ h4 = (const int4*)hin;
    const int e0 = off[n], e1 = off[n + 1];
    float acc[8] = {0.f, 0.f, 0.f, 0.f, 0.f, 0.f, 0.f, 0.f};
    for (int base = e0; base < e1; base += ES) {
        const int ee = base + es;
        const unsigned int r = (ee < e1) ? recs[ee] : 0u;
        const float w = hbits2f((r & 0x7FFFu) << 1);
        const int4 g = h4[(size_t)(r >> 15) * S4 + q];
        float2 t;
        t = i2f2(g.x); acc[0] += w * t.x; acc[1] += w * t.y;
        t = i2f2(g.y); acc[2] += w * t.x; acc[3] += w * t.y;
        t = i2f2(g.z); acc[4] += w * t.x; acc[5] += w * t.y;
        t = i2f2(g.w); acc[6] += w * t.x; acc[7] += w * t.y;
    }
#pragma unroll
    for (int d = Q; d < GS; d <<= 1) {
#pragma unroll
        for (int j = 0; j < 8; ++j) acc[j] += __shfl_xor(acc[j], d);
    }
    if (gl < Q) {
        int4 o;
        o.x = f2i2(acc[0], acc[1]);
        o.y = f2i2(acc[2], acc[3]);
        o.z = f2i2(acc[4], acc[5]);
        o.w = f2i2(acc[6], acc[7]);
        ((int4*)hout)[(size_t)n * S4 + q] = o;
    }
}

// ---------------- MFMA concat-GEMM: out = relu(A[N][K] @ W[K][64] + b) ----------------

template <int K>
__global__ __launch_bounds__(256) void gemmcat_mfma(const __half* __restrict__ A,
                                                    const __half* __restrict__ Bp,
                                                    const float* __restrict__ bias,
                                                    __half* __restrict__ out, int N) {
    __shared__ __half hs[128][72];
    const int wave = threadIdx.x >> 6;
    const int lane = threadIdx.x & 63;
    const int nb = blockIdx.x * 128 + wave * 32;
    const int m = lane & 15;
    const int kg = lane >> 4;

    const int row0 = min(nb + m, N - 1);
    const int row1 = min(nb + 16 + m, N - 1);
    const f16x8* a0p = (const f16x8*)(A + (size_t)row0 * K + kg * 8);
    const f16x8* a1p = (const f16x8*)(A + (size_t)row1 * K + kg * 8);
    const f16x8* bp = (const f16x8*)Bp + lane;

    f32x4 acc[2][4];
#pragma unroll
    for (int nt = 0; nt < 4; ++nt) {
        const float bv = bias[nt * 16 + m];
        acc[0][nt] = (f32x4){bv, bv, bv, bv};
        acc[1][nt] = (f32x4){bv, bv, bv, bv};
    }

#pragma unroll
    for (int kk = 0; kk < K / 32; ++kk) {
        const f16x8 a0 = a0p[kk * 4];
        const f16x8 a1 = a1p[kk * 4];
#pragma unroll
        for (int nt = 0; nt < 4; ++nt) {
            const f16x8 b = bp[(kk * 4 + nt) * 64];
            acc[0][nt] = __builtin_amdgcn_mfma_f32_16x16x32_f16(a0, b, acc[0][nt], 0, 0, 0);
            acc[1][nt] = __builtin_amdgcn_mfma_f32_16x16x32_f16(a1, b, acc[1][nt], 0, 0, 0);
        }
    }

#pragma unroll
    for (int mt = 0; mt < 2; ++mt) {
#pragma unroll
        for (int nt = 0; nt < 4; ++nt) {
#pragma unroll
            for (int r = 0; r < 4; ++r) {
                const int nl = wave * 32 + mt * 16 + kg * 4 + r;
                hs[nl][nt * 16 + m] = __float2half(fmaxf(acc[mt][nt][r], 0.f));
            }
        }
    }
    __syncthreads();
    const int nl = threadIdx.x >> 1;
    const int seg = threadIdx.x & 1;
    const int node = blockIdx.x * 128 + nl;
    if (node >= N) return;
    const int4* src = (const int4*)&hs[nl][seg * 32];
    int4* dst = (int4*)(out + (size_t)node * 256 + seg * 32);
    dst[0] = src[0];
    dst[1] = src[1];
    dst[2] = src[2];
    dst[3] = src[3];
}

// ---------------- layer 4: four 4-dim projections from fp16 h (stride 256) ----------------

__global__ __launch_bounds__(256) void proj4h_kernel(const __half* __restrict__ h,
                                                     const float* __restrict__ W,
                                                     float* __restrict__ P0,
                                                     float* __restrict__ P1,
                                                     float* __restrict__ P2,
                                                     float* __restrict__ P3, int nNodes) {
    __shared__ float Ws[4 * 64 * 4];
    for (int i = threadIdx.x; i < 1024; i += 256) Ws[i] = W[i];
    __syncthreads();
    const int k = threadIdx.x & 3;
    const int n = blockIdx.x * 64 + (threadIdx.x >> 2);
    if (n >= nNodes) return;
    const int4* __restrict__ h8 = (const int4*)h + (size_t)n * 32;
    const float4* W4 = (const float4*)(Ws + k * 256);
    float4 acc = make_float4(0.f, 0.f, 0.f, 0.f);
#pragma unroll
    for (int i8 = 0; i8 < 8; ++i8) {
        const int4 g = h8[i8];
        const float2 f0 = i2f2(g.x), f1 = i2f2(g.y), f2v = i2f2(g.z), f3 = i2f2(g.w);
        const float hv[8] = {f0.x, f0.y, f1.x, f1.y, f2v.x, f2v.y, f3.x, f3.y};
#pragma unroll
        for (int j = 0; j < 8; ++j) {
            const float4 wr = W4[i8 * 8 + j];
            acc.x += hv[j] * wr.x;
            acc.y += hv[j] * wr.y;
            acc.z += hv[j] * wr.z;
            acc.w += hv[j] * wr.w;
        }
    }
    float4* dst = (k == 0) ? (float4*)P0 : (k == 1) ? (float4*)P1 : (k == 2) ? (float4*)P2
                                                                             : (float4*)P3;
    dst[n] = acc;
}

// Layer-4 Horner hop, wave-grouped: 16-lane group per node, 4 nodes/wave.
// out[n] = P[n] (+bias) + sum_e norm_e * U[src_e]
template <bool FINAL>
__global__ __launch_bounds__(256) void prop1w_kernel(const int* __restrict__ off,
                                                     const unsigned int* __restrict__ recs,
                                                     const float* __restrict__ Uin,
                                                     const float* __restrict__ P,
                                                     const float* __restrict__ b,
                                                     float* __restrict__ out, int nNodes) {
    const int wid = (blockIdx.x * 256 + threadIdx.x) >> 6;
    const int lane = threadIdx.x & 63;
    const int n = wid * 4 + (lane >> 4);
    if (n >= nNodes) return;
    const int es = lane & 15;
    const float4* __restrict__ u4 = (const float4*)Uin;
    const int e0 = off[n], e1 = off[n + 1];
    float4 acc = make_float4(0.f, 0.f, 0.f, 0.f);
    for (int base = e0; base < e1; base += 16) {
        const int ee = base + es;
        const unsigned int r = (ee < e1) ? recs[ee] : 0u;
        const float w = hbits2f((r & 0x7FFFu) << 1);
        const float4 u = u4[r >> 15];
        acc.x += w * u.x;
        acc.y += w * u.y;
        acc.z += w * u.z;
        acc.w += w * u.w;
    }
#pragma unroll
    for (int d = 1; d < 16; d <<= 1) {
        acc.x += __shfl_xor(acc.x, d);
        acc.y += __shfl_xor(acc.y, d);
        acc.z += __shfl_xor(acc.z, d);
        acc.w += __shfl_xor(acc.w, d);
    }
    if (es == 0) {
        const float4 pv = ((const float4*)P)[n];
        acc.x += pv.x;
        acc.y += pv.y;
        acc.z += pv.z;
        acc.w += pv.w;
        if (FINAL) {
            const float4 bv = *(const float4*)b;
            acc.x += bv.x;
            acc.y += bv.y;
            acc.z += bv.z;
            acc.w += bv.w;
        }
        ((float4*)out)[n] = acc;
    }
}

// ---------------- host ----------------

extern "C" void kernel_launch(void* const* d_in, const int* in_sizes, int n_in,
                              void* d_out, int out_size, void* d_ws, size_t ws_size,
                              hipStream_t stream) {
    const float* x = (const float*)d_in[0];
    const int* ei = (const int*)d_in[1];
    const float* W[5] = {(const float*)d_in[2], (const float*)d_in[4], (const float*)d_in[6],
                         (const float*)d_in[8], (const float*)d_in[10]};
    const float* bb[5] = {(const float*)d_in[3], (const float*)d_in[5], (const float*)d_in[7],
                          (const float*)d_in[9], (const float*)d_in[11]};
    const int E = in_sizes[1] / 2;   // 800000
    const int N = in_sizes[0] / 16;  // 50000
    float* outp = (float*)d_out;

    char* p = (char*)d_ws;
    auto alloc = [&](size_t bytes) {
        char* r = p;
        p += (bytes + 255) & ~size_t(255);
        return r;
    };
    const int nb = (N + 255) / 256;
    int* cnt = (int*)alloc((size_t)N * 4);
    int* off = (int*)alloc((size_t)(N + 1) * 4);
    float* dinv = (float*)alloc((size_t)N * 4);
    int* bsum = (int*)alloc((size_t)nb * 4);
    unsigned short* rank = (unsigned short*)alloc((size_t)E * 2);
    unsigned int* recs = (unsigned int*)alloc((size_t)E * 4);
    __half* xcat = (__half*)alloc((size_t)N * 64 * 2);
    __half* hcatA = (__half*)alloc((size_t)N * 256 * 2);
    __half* hcatB = (__half*)alloc((size_t)N * 256 * 2);
    __half* Bp0 = (__half*)alloc((size_t)512 * 8 * 2);
    __half* Bp1 = (__half*)alloc((size_t)2048 * 8 * 2);
    __half* Bp2 = (__half*)alloc((size_t)2048 * 8 * 2);
    __half* Bp3 = (__half*)alloc((size_t)2048 * 8 * 2);
    float* P0 = (float*)alloc((size_t)N * 4 * 4);
    float* P1 = (float*)alloc((size_t)N * 4 * 4);
    float* P2 = (float*)alloc((size_t)N * 4 * 4);
    float* P3 = (float*)alloc((size_t)N * 4 * 4);
    float* Ua = (float*)alloc((size_t)N * 4 * 4);
    float* Ub = (float*)alloc((size_t)N * 4 * 4);

    hipMemsetAsync(cnt, 0, (size_t)N * 4, stream);
    const int eb = (E + 255) / 256;
    count_rank_kernel<<<eb, 256, 0, stream>>>(ei + E, cnt, rank, E);
    scan_block_kernel<<<nb, 256, 0, stream>>>(cnt, off, bsum, N);
    scan_apply_kernel<<<nb, 256, 0, stream>>>(off, bsum, N, E);
    const int prep_total = 3 * N + 512 + 3 * 2048;
    prep_kernel<<<(prep_total + 255) / 256, 256, 0, stream>>>(
        cnt, dinv, x, xcat, W[0], W[1], W[2], W[3], Bp0, Bp1, Bp2, Bp3, N);
    scatter_kernel<<<eb, 256, 0, stream>>>(ei, ei + E, off, rank, dinv, recs, E);

    // wave-per-node grids
    const int gw64 = (N * 64 + 255) / 256;              // NPW=1 (64-dim rows)
    const int gw16 = (((N + 1) / 2) * 64 + 255) / 256;  // NPW=2 (16-dim rows)
    const int gw4 = (((N + 3) / 4) * 64 + 255) / 256;   // NPW=4 (4-dim fp32 rows)
    const int gm = (N + 127) / 128;
    const int gq = (N + 63) / 64;

    // Layer 0: hops fill xcat col-slices (16-dim); MFMA GEMM K=64 -> hcatA cols 0..63
    gatherw_kernel<16, 2, 8><<<gw16, 256, 0, stream>>>(off, recs, xcat + 0, xcat + 16, N);
    gatherw_kernel<16, 2, 8><<<gw16, 256, 0, stream>>>(off, recs, xcat + 16, xcat + 32, N);
    gatherw_kernel<16, 2, 8><<<gw16, 256, 0, stream>>>(off, recs, xcat + 32, xcat + 48, N);
    gemmcat_mfma<64><<<gm, 256, 0, stream>>>(xcat, Bp0, bb[0], hcatA, N);

    // Layers 1-3: hops fill hcat col-slices (64-dim); MFMA GEMM K=256
    __half* cur = hcatA;
    __half* nxt = hcatB;
    const __half* Bps[4] = {nullptr, Bp1, Bp2, Bp3};
    for (int l = 1; l <= 3; ++l) {
        gatherw_kernel<8, 8, 32><<<gw64, 256, 0, stream>>>(off, recs, cur + 0, cur + 64, N);
        gatherw_kernel<8, 8, 32><<<gw64, 256, 0, stream>>>(off, recs, cur + 64, cur + 128, N);
        gatherw_kernel<8, 8, 32><<<gw64, 256, 0, stream>>>(off, recs, cur + 128, cur + 192, N);
        gemmcat_mfma<256><<<gm, 256, 0, stream>>>(cur, Bps[l], bb[l], nxt, N);
        __half* t = cur;
        cur = nxt;
        nxt = t;
    }

    // Layer 4: P_k = cur@W4_k (one fp16 read of cur), Horner on 4-dim fp32 signals
    proj4h_kernel<<<gq, 256, 0, stream>>>(cur, W[4], P0, P1, P2, P3, N);
    prop1w_kernel<false><<<gw4, 256, 0, stream>>>(off, recs, P3, P2, nullptr, Ua, N);
    prop1w_kernel<false><<<gw4, 256, 0, stream>>>(off, recs, Ua, P1, nullptr, Ub, N);
    prop1w_kernel<true><<<gw4, 256, 0, stream>>>(off, recs, Ub, P0, bb[4], outp, N);
}

// Round 10
// 294.573 us; speedup vs baseline: 1.2950x; 1.2950x over previous
//
#include <hip/hip_runtime.h>
#include <hip/hip_fp16.h>

typedef _Float16 f16x8 __attribute__((ext_vector_type(8)));
typedef float f32x4 __attribute__((ext_vector_type(4)));

// ---------------- fp16 helpers ----------------
union H2I { int i; __half2 h; };
static __device__ inline float2 i2f2(int v) {
    H2I u; u.i = v; return __half22float2(u.h);
}
static __device__ inline int f2i2(float a, float b) {
    H2I u; u.h = __floats2half2_rn(a, b); return u.i;
}
static __device__ inline __half2 i2h2(int v) {
    H2I u; u.i = v; return u.h;
}
static __device__ inline int h22i(__half2 h) {
    H2I u; u.h = h; return u.i;
}
static __device__ inline float hbits2f(unsigned int b) {
    union { unsigned short s; __half h; } u;
    u.s = (unsigned short)b;
    return __half2float(u.h);
}
// weight half2 straight from packed record bits (no float conversion)
static __device__ inline __half2 wof(unsigned int r) {
    union { unsigned short s; __half h; } u;
    u.s = (unsigned short)((r & 0x7FFFu) << 1);
    return __half2half2(u.h);
}

struct H8 { __half2 a, b, c, d; };
static __device__ inline void pkfma(H8& s, int4 g, __half2 ww) {
    s.a = __hfma2(i2h2(g.x), ww, s.a);
    s.b = __hfma2(i2h2(g.y), ww, s.b);
    s.c = __hfma2(i2h2(g.z), ww, s.c);
    s.d = __hfma2(i2h2(g.w), ww, s.d);
}

// ---------------- CSR build ----------------

__global__ __launch_bounds__(256) void count_rank_kernel(const int* __restrict__ col,
                                                         int* __restrict__ cnt,
                                                         unsigned short* __restrict__ rank,
                                                         int E) {
    int e = blockIdx.x * 256 + threadIdx.x;
    if (e < E) rank[e] = (unsigned short)atomicAdd(&cnt[col[e]], 1);
}

__global__ __launch_bounds__(256) void scan_block_kernel(const int* __restrict__ cnt,
                                                         int* __restrict__ off,
                                                         int* __restrict__ bsum, int n) {
    const int gid = blockIdx.x * 256 + threadIdx.x;
    const int v = (gid < n) ? cnt[gid] : 0;
    const int lane = threadIdx.x & 63, w = threadIdx.x >> 6;
    int x = v;
#pragma unroll
    for (int d = 1; d < 64; d <<= 1) {
        int t = __shfl_up(x, d);
        if (lane >= d) x += t;
    }
    __shared__ int wt[4];
    if (lane == 63) wt[w] = x;
    __syncthreads();
    int base = 0;
#pragma unroll
    for (int i = 0; i < 3; ++i)
        if (i < w) base += wt[i];
    const int incl = base + x;
    if (gid < n) off[gid] = incl - v;
    if (threadIdx.x == 255) bsum[blockIdx.x] = incl;
}

// Merged: each block computes its own bsum prefix, applies, sets off[n].
__global__ __launch_bounds__(256) void scan_apply_kernel(int* __restrict__ off,
                                                         const int* __restrict__ bsum,
                                                         int n, int E) {
    __shared__ int sbase;
    const int tid = threadIdx.x;
    if (tid < 64) {
        int s = 0;
        for (int i = tid; i < blockIdx.x; i += 64) s += bsum[i];
#pragma unroll
        for (int d = 1; d < 64; d <<= 1) s += __shfl_xor(s, d);
        if (tid == 0) sbase = s;
    }
    __syncthreads();
    const int gid = blockIdx.x * 256 + tid;
    if (gid < n) off[gid] += sbase;
    if (gid == n) off[n] = E;
}

// Fused prep: dinv (N), x->xcat fp16 (2N), packB for 4 layers (512 + 3*2048).
__global__ __launch_bounds__(256) void prep_kernel(const int* __restrict__ cnt,
                                                   float* __restrict__ dinv,
                                                   const float* __restrict__ x,
                                                   __half* __restrict__ xcat,
                                                   const float* __restrict__ W0,
                                                   const float* __restrict__ W1,
                                                   const float* __restrict__ W2,
                                                   const float* __restrict__ W3,
                                                   __half* __restrict__ Bp0,
                                                   __half* __restrict__ Bp1,
                                                   __half* __restrict__ Bp2,
                                                   __half* __restrict__ Bp3, int N) {
    int t = blockIdx.x * 256 + threadIdx.x;
    if (t < N) {
        const int c = cnt[t];
        dinv[t] = (c > 0) ? 1.0f / sqrtf((float)c) : 0.0f;
        return;
    }
    t -= N;
    if (t < 2 * N) {
        const int n = t >> 1, q = t & 1;
        const float4 v0 = ((const float4*)x)[n * 4 + q * 2 + 0];
        const float4 v1 = ((const float4*)x)[n * 4 + q * 2 + 1];
        int4 o;
        o.x = f2i2(v0.x, v0.y);
        o.y = f2i2(v0.z, v0.w);
        o.z = f2i2(v1.x, v1.y);
        o.w = f2i2(v1.z, v1.w);
        ((int4*)xcat)[n * 8 + q] = o;
        return;
    }
    t -= 2 * N;
    const float* W;
    __half* Bp;
    if (t < 512) {
        W = W0; Bp = Bp0;
    } else if (t < 512 + 2048) {
        W = W1; Bp = Bp1; t -= 512;
    } else if (t < 512 + 2 * 2048) {
        W = W2; Bp = Bp2; t -= 512 + 2048;
    } else if (t < 512 + 3 * 2048) {
        W = W3; Bp = Bp3; t -= 512 + 2 * 2048;
    } else {
        return;
    }
    const int kk = t >> 8;
    const int nt = (t >> 6) & 3;
    const int l = t & 63;
    const int m = l & 15, kg = l >> 4;
    const int col = nt * 16 + m;
    __half tmp[8];
#pragma unroll
    for (int j = 0; j < 8; ++j) {
        const int k = kk * 32 + kg * 8 + j;
        tmp[j] = __float2half(W[k * 64 + col]);
    }
    ((int4*)Bp)[t] = *(int4*)tmp;
}

// Scatter edge -> packed record: src (17 bits) | norm (15-bit fp16, sign+LSB dropped).
__global__ __launch_bounds__(256) void scatter_kernel(const int* __restrict__ row,
                                                      const int* __restrict__ col,
                                                      const int* __restrict__ off,
                                                      const unsigned short* __restrict__ rank,
                                                      const float* __restrict__ dinv,
                                                      unsigned int* __restrict__ recs, int E) {
    int e = blockIdx.x * 256 + threadIdx.x;
    if (e >= E) return;
    const int r = row[e], c = col[e];
    const int pos = off[c] + (int)rank[e];
    const unsigned int nb = (unsigned int)__half_as_ushort(__float2half_rn(dinv[r] * dinv[c]));
    recs[pos] = ((unsigned int)r << 15) | (nb >> 1);
}

// ---------------- fp16 hop: out-slice = A_norm * in-slice ----------------
// DQ lanes/node, each owns one int4 (8 halfs). S4 = row stride in int4 units.
// Packed-fp16 accumulate (v_pk_fma_f16); weight decoded from rec bits, no cvt.

template <int DQ, int S4>
__global__ __launch_bounds__(256) void gatherh_kernel(const int* __restrict__ off,
                                                      const unsigned int* __restrict__ recs,
                                                      const __half* __restrict__ hin,
                                                      __half* __restrict__ hout, int nNodes) {
    const int t = blockIdx.x * 256 + threadIdx.x;
    const int n = t / DQ;
    const int q = t & (DQ - 1);
    if (n >= nNodes) return;
    const int4* __restrict__ h4 = (const int4*)hin;
    H8 s;
    s.a = __float2half2_rn(0.f);
    s.b = __float2half2_rn(0.f);
    s.c = __float2half2_rn(0.f);
    s.d = __float2half2_rn(0.f);
    int e = off[n];
    const int e1 = off[n + 1];
    for (; e + 8 <= e1; e += 8) {
        const unsigned int r0 = recs[e + 0];
        const unsigned int r1 = recs[e + 1];
        const unsigned int r2 = recs[e + 2];
        const unsigned int r3 = recs[e + 3];
        const unsigned int r4 = recs[e + 4];
        const unsigned int r5 = recs[e + 5];
        const unsigned int r6 = recs[e + 6];
        const unsigned int r7 = recs[e + 7];
        const int4 g0 = h4[(size_t)(r0 >> 15) * S4 + q];
        const int4 g1 = h4[(size_t)(r1 >> 15) * S4 + q];
        const int4 g2 = h4[(size_t)(r2 >> 15) * S4 + q];
        const int4 g3 = h4[(size_t)(r3 >> 15) * S4 + q];
        const int4 g4 = h4[(size_t)(r4 >> 15) * S4 + q];
        const int4 g5 = h4[(size_t)(r5 >> 15) * S4 + q];
        const int4 g6 = h4[(size_t)(r6 >> 15) * S4 + q];
        const int4 g7 = h4[(size_t)(r7 >> 15) * S4 + q];
        pkfma(s, g0, wof(r0));
        pkfma(s, g1, wof(r1));
        pkfma(s, g2, wof(r2));
        pkfma(s, g3, wof(r3));
        pkfma(s, g4, wof(r4));
        pkfma(s, g5, wof(r5));
        pkfma(s, g6, wof(r6));
        pkfma(s, g7, wof(r7));
    }
    for (; e + 4 <= e1; e += 4) {
        const unsigned int r0 = recs[e + 0];
        const unsigned int r1 = recs[e + 1];
        const unsigned int r2 = recs[e + 2];
        const unsigned int r3 = recs[e + 3];
        const int4 g0 = h4[(size_t)(r0 >> 15) * S4 + q];
        const int4 g1 = h4[(size_t)(r1 >> 15) * S4 + q];
        const int4 g2 = h4[(size_t)(r2 >> 15) * S4 + q];
        const int4 g3 = h4[(size_t)(r3 >> 15) * S4 + q];
        pkfma(s, g0, wof(r0));
        pkfma(s, g1, wof(r1));
        pkfma(s, g2, wof(r2));
        pkfma(s, g3, wof(r3));
    }
    for (; e < e1; ++e) {
        const unsigned int r = recs[e];
        pkfma(s, h4[(size_t)(r >> 15) * S4 + q], wof(r));
    }
    int4 o;
    o.x = h22i(s.a);
    o.y = h22i(s.b);
    o.z = h22i(s.c);
    o.w = h22i(s.d);
    ((int4*)hout)[(size_t)n * S4 + q] = o;
}

// ---------------- MFMA concat-GEMM: out = relu(A[N][K] @ W[K][64] + b) ----------------
// PROJ: instead of writing the fp16 row, compute P_k = row @ W4_k (k=0..3) in-block.

template <int K, bool PROJ>
__global__ __launch_bounds__(256) void gemmcat_mfma(const __half* __restrict__ A,
                                                    const __half* __restrict__ Bp,
                                                    const float* __restrict__ bias,
                                                    __half* __restrict__ out,
                                                    const float* __restrict__ W4,
                                                    float* __restrict__ P, int N) {
    __shared__ __half hs[128][72];
    __shared__ float W4s[PROJ ? 1024 : 1];
    if (PROJ) {
        for (int i = threadIdx.x; i < 1024; i += 256) W4s[i] = W4[i];
    }
    const int wave = threadIdx.x >> 6;
    const int lane = threadIdx.x & 63;
    const int nb = blockIdx.x * 128 + wave * 32;
    const int m = lane & 15;
    const int kg = lane >> 4;

    const int row0 = min(nb + m, N - 1);
    const int row1 = min(nb + 16 + m, N - 1);
    const f16x8* a0p = (const f16x8*)(A + (size_t)row0 * K + kg * 8);
    const f16x8* a1p = (const f16x8*)(A + (size_t)row1 * K + kg * 8);
    const f16x8* bp = (const f16x8*)Bp + lane;

    f32x4 acc[2][4];
#pragma unroll
    for (int nt = 0; nt < 4; ++nt) {
        const float bv = bias[nt * 16 + m];
        acc[0][nt] = (f32x4){bv, bv, bv, bv};
        acc[1][nt] = (f32x4){bv, bv, bv, bv};
    }

#pragma unroll
    for (int kk = 0; kk < K / 32; ++kk) {
        const f16x8 a0 = a0p[kk * 4];
        const f16x8 a1 = a1p[kk * 4];
#pragma unroll
        for (int nt = 0; nt < 4; ++nt) {
            const f16x8 b = bp[(kk * 4 + nt) * 64];
            acc[0][nt] = __builtin_amdgcn_mfma_f32_16x16x32_f16(a0, b, acc[0][nt], 0, 0, 0);
            acc[1][nt] = __builtin_amdgcn_mfma_f32_16x16x32_f16(a1, b, acc[1][nt], 0, 0, 0);
        }
    }

#pragma unroll
    for (int mt = 0; mt < 2; ++mt) {
#pragma unroll
        for (int nt = 0; nt < 4; ++nt) {
#pragma unroll
            for (int r = 0; r < 4; ++r) {
                const int nl = wave * 32 + mt * 16 + kg * 4 + r;
                hs[nl][nt * 16 + m] = __float2half(fmaxf(acc[mt][nt][r], 0.f));
            }
        }
    }
    __syncthreads();
    if (!PROJ) {
        const int nl = threadIdx.x >> 1;
        const int seg = threadIdx.x & 1;
        const int node = blockIdx.x * 128 + nl;
        if (node >= N) return;
        const int4* src = (const int4*)&hs[nl][seg * 32];
        int4* dst = (int4*)(out + (size_t)node * 256 + seg * 32);
        dst[0] = src[0];
        dst[1] = src[1];
        dst[2] = src[2];
        dst[3] = src[3];
    } else {
        // thread pair per node: hf selects k-pair {2hf, 2hf+1}
        const int nl = threadIdx.x >> 1;
        const int hf = threadIdx.x & 1;
        const int node = blockIdx.x * 128 + nl;
        if (node >= N) return;
        float p0x = 0.f, p0y = 0.f, p0z = 0.f, p0w = 0.f;
        float p1x = 0.f, p1y = 0.f, p1z = 0.f, p1w = 0.f;
        const int4* hrow = (const int4*)&hs[nl][0];
#pragma unroll
        for (int i8 = 0; i8 < 8; ++i8) {
            const int4 g = hrow[i8];
            const float2 f0 = i2f2(g.x), f1 = i2f2(g.y), f2v = i2f2(g.z), f3 = i2f2(g.w);
            const float hv[8] = {f0.x, f0.y, f1.x, f1.y, f2v.x, f2v.y, f3.x, f3.y};
#pragma unroll
            for (int j = 0; j < 8; ++j) {
                const int i = i8 * 8 + j;
                const float4 w0 = *(const float4*)&W4s[(hf * 2 + 0) * 256 + i * 4];
                const float4 w1 = *(const float4*)&W4s[(hf * 2 + 1) * 256 + i * 4];
                p0x += hv[j] * w0.x; p0y += hv[j] * w0.y;
                p0z += hv[j] * w0.z; p0w += hv[j] * w0.w;
                p1x += hv[j] * w1.x; p1y += hv[j] * w1.y;
                p1z += hv[j] * w1.z; p1w += hv[j] * w1.w;
            }
        }
        ((float4*)P)[(size_t)(hf * 2 + 0) * N + node] = make_float4(p0x, p0y, p0z, p0w);
        ((float4*)P)[(size_t)(hf * 2 + 1) * N + node] = make_float4(p1x, p1y, p1z, p1w);
    }
}

// Horner step on 4-dim fp32 signals: out[n] = P[n] (+bias) + sum_e norm_e * U[src_e]
template <bool FINAL>
__global__ __launch_bounds__(256) void prop1_add_kernel(const int* __restrict__ off,
                                                        const unsigned int* __restrict__ recs,
                                                        const float* __restrict__ Uin,
                                                        const float* __restrict__ P,
                                                        const float* __restrict__ b,
                                                        float* __restrict__ out, int nNodes) {
    const int n = blockIdx.x * 256 + threadIdx.x;
    if (n >= nNodes) return;
    const float4* __restrict__ u4 = (const float4*)Uin;
    float4 acc = ((const float4*)P)[n];
    if (FINAL) {
        const float4 bv = *(const float4*)b;
        acc.x += bv.x;
        acc.y += bv.y;
        acc.z += bv.z;
        acc.w += bv.w;
    }
    int e = off[n];
    const int e1 = off[n + 1];
    for (; e + 4 <= e1; e += 4) {
        const unsigned int r0 = recs[e + 0];
        const unsigned int r1 = recs[e + 1];
        const unsigned int r2 = recs[e + 2];
        const unsigned int r3 = recs[e + 3];
        const float4 a = u4[r0 >> 15], bb = u4[r1 >> 15];
        const float4 c = u4[r2 >> 15], d = u4[r3 >> 15];
        const float w0 = hbits2f((r0 & 0x7FFFu) << 1);
        const float w1 = hbits2f((r1 & 0x7FFFu) << 1);
        const float w2 = hbits2f((r2 & 0x7FFFu) << 1);
        const float w3 = hbits2f((r3 & 0x7FFFu) << 1);
        acc.x += w0 * a.x + w1 * bb.x + w2 * c.x + w3 * d.x;
        acc.y += w0 * a.y + w1 * bb.y + w2 * c.y + w3 * d.y;
        acc.z += w0 * a.z + w1 * bb.z + w2 * c.z + w3 * d.z;
        acc.w += w0 * a.w + w1 * bb.w + w2 * c.w + w3 * d.w;
    }
    for (; e < e1; ++e) {
        const unsigned int r = recs[e];
        const float ww = hbits2f((r & 0x7FFFu) << 1);
        const float4 hv = u4[r >> 15];
        acc.x += ww * hv.x;
        acc.y += ww * hv.y;
        acc.z += ww * hv.z;
        acc.w += ww * hv.w;
    }
    ((float4*)out)[n] = acc;
}

// ---------------- host ----------------

extern "C" void kernel_launch(void* const* d_in, const int* in_sizes, int n_in,
                              void* d_out, int out_size, void* d_ws, size_t ws_size,
                              hipStream_t stream) {
    const float* x = (const float*)d_in[0];
    const int* ei = (const int*)d_in[1];
    const float* W[5] = {(const float*)d_in[2], (const float*)d_in[4], (const float*)d_in[6],
                         (const float*)d_in[8], (const float*)d_in[10]};
    const float* bb[5] = {(const float*)d_in[3], (const float*)d_in[5], (const float*)d_in[7],
                          (const float*)d_in[9], (const float*)d_in[11]};
    const int E = in_sizes[1] / 2;   // 800000
    const int N = in_sizes[0] / 16;  // 50000
    float* outp = (float*)d_out;

    char* p = (char*)d_ws;
    auto alloc = [&](size_t bytes) {
        char* r = p;
        p += (bytes + 255) & ~size_t(255);
        return r;
    };
    const int nb = (N + 255) / 256;
    int* cnt = (int*)alloc((size_t)N * 4);
    int* off = (int*)alloc((size_t)(N + 1) * 4);
    float* dinv = (float*)alloc((size_t)N * 4);
    int* bsum = (int*)alloc((size_t)nb * 4);
    unsigned short* rank = (unsigned short*)alloc((size_t)E * 2);
    unsigned int* recs = (unsigned int*)alloc((size_t)E * 4);
    __half* xcat = (__half*)alloc((size_t)N * 64 * 2);
    __half* hcatA = (__half*)alloc((size_t)N * 256 * 2);
    __half* hcatB = (__half*)alloc((size_t)N * 256 * 2);
    __half* Bp0 = (__half*)alloc((size_t)512 * 8 * 2);
    __half* Bp1 = (__half*)alloc((size_t)2048 * 8 * 2);
    __half* Bp2 = (__half*)alloc((size_t)2048 * 8 * 2);
    __half* Bp3 = (__half*)alloc((size_t)2048 * 8 * 2);
    float* Pall = (float*)alloc((size_t)4 * N * 4 * 4);  // P_k[n][4], k-major
    float* Ua = (float*)alloc((size_t)N * 4 * 4);
    float* Ub = (float*)alloc((size_t)N * 4 * 4);

    hipMemsetAsync(cnt, 0, (size_t)N * 4, stream);
    const int eb = (E + 255) / 256;
    count_rank_kernel<<<eb, 256, 0, stream>>>(ei + E, cnt, rank, E);
    scan_block_kernel<<<nb, 256, 0, stream>>>(cnt, off, bsum, N);
    scan_apply_kernel<<<nb, 256, 0, stream>>>(off, bsum, N, E);
    const int prep_total = 3 * N + 512 + 3 * 2048;
    prep_kernel<<<(prep_total + 255) / 256, 256, 0, stream>>>(
        cnt, dinv, x, xcat, W[0], W[1], W[2], W[3], Bp0, Bp1, Bp2, Bp3, N);
    scatter_kernel<<<eb, 256, 0, stream>>>(ei, ei + E, off, rank, dinv, recs, E);

    const int gh2 = (N * 2 + 255) / 256;   // DQ=2 hop grid
    const int gh8 = (N * 8 + 255) / 256;   // DQ=8 hop grid
    const int gm = (N + 127) / 128;        // MFMA gemm grid
    const int p1 = (N + 255) / 256;

    // Layer 0: hops fill xcat col-slices (16-dim); MFMA GEMM K=64 -> hcatA cols 0..63
    gatherh_kernel<2, 8><<<gh2, 256, 0, stream>>>(off, recs, xcat + 0, xcat + 16, N);
    gatherh_kernel<2, 8><<<gh2, 256, 0, stream>>>(off, recs, xcat + 16, xcat + 32, N);
    gatherh_kernel<2, 8><<<gh2, 256, 0, stream>>>(off, recs, xcat + 32, xcat + 48, N);
    gemmcat_mfma<64, false><<<gm, 256, 0, stream>>>(xcat, Bp0, bb[0], hcatA, nullptr,
                                                    nullptr, N);

    // Layers 1-2: hops + MFMA GEMM K=256 (write next hcat)
    __half* cur = hcatA;
    __half* nxt = hcatB;
    const __half* Bps[4] = {nullptr, Bp1, Bp2, Bp3};
    for (int l = 1; l <= 2; ++l) {
        gatherh_kernel<8, 32><<<gh8, 256, 0, stream>>>(off, recs, cur + 0, cur + 64, N);
        gatherh_kernel<8, 32><<<gh8, 256, 0, stream>>>(off, recs, cur + 64, cur + 128, N);
        gatherh_kernel<8, 32><<<gh8, 256, 0, stream>>>(off, recs, cur + 128, cur + 192, N);
        gemmcat_mfma<256, false><<<gm, 256, 0, stream>>>(cur, Bps[l], bb[l], nxt, nullptr,
                                                         nullptr, N);
        __half* t = cur;
        cur = nxt;
        nxt = t;
    }

    // Layer 3: hops + MFMA GEMM with fused proj4 epilogue (no hcat write)
    gatherh_kernel<8, 32><<<gh8, 256, 0, stream>>>(off, recs, cur + 0, cur + 64, N);
    gatherh_kernel<8, 32><<<gh8, 256, 0, stream>>>(off, recs, cur + 64, cur + 128, N);
    gatherh_kernel<8, 32><<<gh8, 256, 0, stream>>>(off, recs, cur + 128, cur + 192, N);
    gemmcat_mfma<256, true><<<gm, 256, 0, stream>>>(cur, Bp3, bb[3], nullptr, W[4], Pall, N);

    // Layer 4 Horner on 4-dim fp32 signals: out = P0 + b + A(P1 + A(P2 + A*P3))
    float* P0 = Pall + (size_t)0 * N * 4;
    float* P1 = Pall + (size_t)1 * N * 4;
    float* P2 = Pall + (size_t)2 * N * 4;
    float* P3 = Pall + (size_t)3 * N * 4;
    prop1_add_kernel<false><<<p1, 256, 0, stream>>>(off, recs, P3, P2, nullptr, Ua, N);
    prop1_add_kernel<false><<<p1, 256, 0, stream>>>(off, recs, Ua, P1, nullptr, Ub, N);
    prop1_add_kernel<true><<<p1, 256, 0, stream>>>(off, recs, Ub, P0, bb[4], outp, N);
}

// Round 12
// 292.686 us; speedup vs baseline: 1.3033x; 1.0064x over previous
//
#include <hip/hip_runtime.h>
#include <hip/hip_fp16.h>

typedef _Float16 f16x8 __attribute__((ext_vector_type(8)));
typedef float f32x4 __attribute__((ext_vector_type(4)));

// ---------------- fp16 helpers ----------------
union H2I { int i; __half2 h; };
static __device__ inline float2 i2f2(int v) {
    H2I u; u.i = v; return __half22float2(u.h);
}
static __device__ inline int f2i2(float a, float b) {
    H2I u; u.h = __floats2half2_rn(a, b); return u.i;
}
static __device__ inline __half2 i2h2(int v) {
    H2I u; u.i = v; return u.h;
}
static __device__ inline int h22i(__half2 h) {
    H2I u; u.h = h; return u.i;
}
static __device__ inline float hbits2f(unsigned int b) {
    union { unsigned short s; __half h; } u;
    u.s = (unsigned short)b;
    return __half2float(u.h);
}
// weight half2 straight from packed record bits (no float conversion)
static __device__ inline __half2 wof(unsigned int r) {
    union { unsigned short s; __half h; } u;
    u.s = (unsigned short)((r & 0x7FFFu) << 1);
    return __half2half2(u.h);
}

struct H8 { __half2 a, b, c, d; };
static __device__ inline void pkfma(H8& s, int4 g, __half2 ww) {
    s.a = __hfma2(i2h2(g.x), ww, s.a);
    s.b = __hfma2(i2h2(g.y), ww, s.b);
    s.c = __hfma2(i2h2(g.z), ww, s.c);
    s.d = __hfma2(i2h2(g.w), ww, s.d);
}

// ---------------- CSR build ----------------

__global__ __launch_bounds__(256) void count_rank_kernel(const int* __restrict__ col,
                                                         int* __restrict__ cnt,
                                                         unsigned short* __restrict__ rank,
                                                         int E) {
    int e = blockIdx.x * 256 + threadIdx.x;
    if (e < E) rank[e] = (unsigned short)atomicAdd(&cnt[col[e]], 1);
}

__global__ __launch_bounds__(256) void scan_block_kernel(const int* __restrict__ cnt,
                                                         int* __restrict__ off,
                                                         int* __restrict__ bsum, int n) {
    const int gid = blockIdx.x * 256 + threadIdx.x;
    const int v = (gid < n) ? cnt[gid] : 0;
    const int lane = threadIdx.x & 63, w = threadIdx.x >> 6;
    int x = v;
#pragma unroll
    for (int d = 1; d < 64; d <<= 1) {
        int t = __shfl_up(x, d);
        if (lane >= d) x += t;
    }
    __shared__ int wt[4];
    if (lane == 63) wt[w] = x;
    __syncthreads();
    int base = 0;
#pragma unroll
    for (int i = 0; i < 3; ++i)
        if (i < w) base += wt[i];
    const int incl = base + x;
    if (gid < n) off[gid] = incl - v;
    if (threadIdx.x == 255) bsum[blockIdx.x] = incl;
}

// Merged: each block computes its own bsum prefix, applies, sets off[n].
__global__ __launch_bounds__(256) void scan_apply_kernel(int* __restrict__ off,
                                                         const int* __restrict__ bsum,
                                                         int n, int E) {
    __shared__ int sbase;
    const int tid = threadIdx.x;
    if (tid < 64) {
        int s = 0;
        for (int i = tid; i < blockIdx.x; i += 64) s += bsum[i];
#pragma unroll
        for (int d = 1; d < 64; d <<= 1) s += __shfl_xor(s, d);
        if (tid == 0) sbase = s;
    }
    __syncthreads();
    const int gid = blockIdx.x * 256 + tid;
    if (gid < n) off[gid] += sbase;
    if (gid == n) off[n] = E;
}

// Fused prep: dinv (N), x->xcat fp16 (2N), packB for 4 layers (512 + 3*2048).
__global__ __launch_bounds__(256) void prep_kernel(const int* __restrict__ cnt,
                                                   float* __restrict__ dinv,
                                                   const float* __restrict__ x,
                                                   __half* __restrict__ xcat,
                                                   const float* __restrict__ W0,
                                                   const float* __restrict__ W1,
                                                   const float* __restrict__ W2,
                                                   const float* __restrict__ W3,
                                                   __half* __restrict__ Bp0,
                                                   __half* __restrict__ Bp1,
                                                   __half* __restrict__ Bp2,
                                                   __half* __restrict__ Bp3, int N) {
    int t = blockIdx.x * 256 + threadIdx.x;
    if (t < N) {
        const int c = cnt[t];
        dinv[t] = (c > 0) ? 1.0f / sqrtf((float)c) : 0.0f;
        return;
    }
    t -= N;
    if (t < 2 * N) {
        const int n = t >> 1, q = t & 1;
        const float4 v0 = ((const float4*)x)[n * 4 + q * 2 + 0];
        const float4 v1 = ((const float4*)x)[n * 4 + q * 2 + 1];
        int4 o;
        o.x = f2i2(v0.x, v0.y);
        o.y = f2i2(v0.z, v0.w);
        o.z = f2i2(v1.x, v1.y);
        o.w = f2i2(v1.z, v1.w);
        ((int4*)xcat)[n * 8 + q] = o;
        return;
    }
    t -= 2 * N;
    const float* W;
    __half* Bp;
    if (t < 512) {
        W = W0; Bp = Bp0;
    } else if (t < 512 + 2048) {
        W = W1; Bp = Bp1; t -= 512;
    } else if (t < 512 + 2 * 2048) {
        W = W2; Bp = Bp2; t -= 512 + 2048;
    } else if (t < 512 + 3 * 2048) {
        W = W3; Bp = Bp3; t -= 512 + 2 * 2048;
    } else {
        return;
    }
    const int kk = t >> 8;
    const int nt = (t >> 6) & 3;
    const int l = t & 63;
    const int m = l & 15, kg = l >> 4;
    const int col = nt * 16 + m;
    __half tmp[8];
#pragma unroll
    for (int j = 0; j < 8; ++j) {
        const int k = kk * 32 + kg * 8 + j;
        tmp[j] = __float2half(W[k * 64 + col]);
    }
    ((int4*)Bp)[t] = *(int4*)tmp;
}

// Scatter edge -> packed record: src (17 bits) | norm (15-bit fp16, sign+LSB dropped).
__global__ __launch_bounds__(256) void scatter_kernel(const int* __restrict__ row,
                                                      const int* __restrict__ col,
                                                      const int* __restrict__ off,
                                                      const unsigned short* __restrict__ rank,
                                                      const float* __restrict__ dinv,
                                                      unsigned int* __restrict__ recs, int E) {
    int e = blockIdx.x * 256 + threadIdx.x;
    if (e >= E) return;
    const int r = row[e], c = col[e];
    const int pos = off[c] + (int)rank[e];
    const unsigned int nb = (unsigned int)__half_as_ushort(__float2half_rn(dinv[r] * dinv[c]));
    recs[pos] = ((unsigned int)r << 15) | (nb >> 1);
}

// ---------------- fp16 hop: out-slice = A_norm * in-slice ----------------
// DQ lanes/node, each owns one int4 (8 halfs). S4 = row stride in int4 units.
// Packed-fp16 accumulate (v_pk_fma_f16); weight decoded from rec bits, no cvt.

template <int DQ, int S4>
__global__ __launch_bounds__(256) void gatherh_kernel(const int* __restrict__ off,
                                                      const unsigned int* __restrict__ recs,
                                                      const __half* __restrict__ hin,
                                                      __half* __restrict__ hout, int nNodes) {
    const int t = blockIdx.x * 256 + threadIdx.x;
    const int n = t / DQ;
    const int q = t & (DQ - 1);
    if (n >= nNodes) return;
    const int4* __restrict__ h4 = (const int4*)hin;
    H8 s;
    s.a = __float2half2_rn(0.f);
    s.b = __float2half2_rn(0.f);
    s.c = __float2half2_rn(0.f);
    s.d = __float2half2_rn(0.f);
    int e = off[n];
    const int e1 = off[n + 1];
    for (; e + 8 <= e1; e += 8) {
        const unsigned int r0 = recs[e + 0];
        const unsigned int r1 = recs[e + 1];
        const unsigned int r2 = recs[e + 2];
        const unsigned int r3 = recs[e + 3];
        const unsigned int r4 = recs[e + 4];
        const unsigned int r5 = recs[e + 5];
        const unsigned int r6 = recs[e + 6];
        const unsigned int r7 = recs[e + 7];
        const int4 g0 = h4[(size_t)(r0 >> 15) * S4 + q];
        const int4 g1 = h4[(size_t)(r1 >> 15) * S4 + q];
        const int4 g2 = h4[(size_t)(r2 >> 15) * S4 + q];
        const int4 g3 = h4[(size_t)(r3 >> 15) * S4 + q];
        const int4 g4 = h4[(size_t)(r4 >> 15) * S4 + q];
        const int4 g5 = h4[(size_t)(r5 >> 15) * S4 + q];
        const int4 g6 = h4[(size_t)(r6 >> 15) * S4 + q];
        const int4 g7 = h4[(size_t)(r7 >> 15) * S4 + q];
        pkfma(s, g0, wof(r0));
        pkfma(s, g1, wof(r1));
        pkfma(s, g2, wof(r2));
        pkfma(s, g3, wof(r3));
        pkfma(s, g4, wof(r4));
        pkfma(s, g5, wof(r5));
        pkfma(s, g6, wof(r6));
        pkfma(s, g7, wof(r7));
    }
    for (; e + 4 <= e1; e += 4) {
        const unsigned int r0 = recs[e + 0];
        const unsigned int r1 = recs[e + 1];
        const unsigned int r2 = recs[e + 2];
        const unsigned int r3 = recs[e + 3];
        const int4 g0 = h4[(size_t)(r0 >> 15) * S4 + q];
        const int4 g1 = h4[(size_t)(r1 >> 15) * S4 + q];
        const int4 g2 = h4[(size_t)(r2 >> 15) * S4 + q];
        const int4 g3 = h4[(size_t)(r3 >> 15) * S4 + q];
        pkfma(s, g0, wof(r0));
        pkfma(s, g1, wof(r1));
        pkfma(s, g2, wof(r2));
        pkfma(s, g3, wof(r3));
    }
    for (; e < e1; ++e) {
        const unsigned int r = recs[e];
        pkfma(s, h4[(size_t)(r >> 15) * S4 + q], wof(r));
    }
    int4 o;
    o.x = h22i(s.a);
    o.y = h22i(s.b);
    o.z = h22i(s.c);
    o.w = h22i(s.d);
    ((int4*)hout)[(size_t)n * S4 + q] = o;
}

// ---------------- MFMA concat-GEMM: out = relu(A[N][K] @ W[K][64] + b) ----------------
// PROJ: instead of writing the fp16 row, compute P_k = row @ W4_k (k=0..3) in-block.

template <int K, bool PROJ>
__global__ __launch_bounds__(256) void gemmcat_mfma(const __half* __restrict__ A,
                                                    const __half* __restrict__ Bp,
                                                    const float* __restrict__ bias,
                                                    __half* __restrict__ out,
                                                    const float* __restrict__ W4,
                                                    float* __restrict__ P, int N) {
    __shared__ __half hs[128][72];
    __shared__ float W4s[PROJ ? 1024 : 1];
    if (PROJ) {
        for (int i = threadIdx.x; i < 1024; i += 256) W4s[i] = W4[i];
    }
    const int wave = threadIdx.x >> 6;
    const int lane = threadIdx.x & 63;
    const int nb = blockIdx.x * 128 + wave * 32;
    const int m = lane & 15;
    const int kg = lane >> 4;

    const int row0 = min(nb + m, N - 1);
    const int row1 = min(nb + 16 + m, N - 1);
    const f16x8* a0p = (const f16x8*)(A + (size_t)row0 * K + kg * 8);
    const f16x8* a1p = (const f16x8*)(A + (size_t)row1 * K + kg * 8);
    const f16x8* bp = (const f16x8*)Bp + lane;

    f32x4 acc[2][4];
#pragma unroll
    for (int nt = 0; nt < 4; ++nt) {
        const float bv = bias[nt * 16 + m];
        acc[0][nt] = (f32x4){bv, bv, bv, bv};
        acc[1][nt] = (f32x4){bv, bv, bv, bv};
    }

#pragma unroll
    for (int kk = 0; kk < K / 32; ++kk) {
        const f16x8 a0 = a0p[kk * 4];
        const f16x8 a1 = a1p[kk * 4];
#pragma unroll
        for (int nt = 0; nt < 4; ++nt) {
            const f16x8 b = bp[(kk * 4 + nt) * 64];
            acc[0][nt] = __builtin_amdgcn_mfma_f32_16x16x32_f16(a0, b, acc[0][nt], 0, 0, 0);
            acc[1][nt] = __builtin_amdgcn_mfma_f32_16x16x32_f16(a1, b, acc[1][nt], 0, 0, 0);
        }
    }

#pragma unroll
    for (int mt = 0; mt < 2; ++mt) {
#pragma unroll
        for (int nt = 0; nt < 4; ++nt) {
#pragma unroll
            for (int r = 0; r < 4; ++r) {
                const int nl = wave * 32 + mt * 16 + kg * 4 + r;
                hs[nl][nt * 16 + m] = __float2half(fmaxf(acc[mt][nt][r], 0.f));
            }
        }
    }
    __syncthreads();
    if (!PROJ) {
        const int nl = threadIdx.x >> 1;
        const int seg = threadIdx.x & 1;
        const int node = blockIdx.x * 128 + nl;
        if (node >= N) return;
        const int4* src = (const int4*)&hs[nl][seg * 32];
        int4* dst = (int4*)(out + (size_t)node * 256 + seg * 32);
        dst[0] = src[0];
        dst[1] = src[1];
        dst[2] = src[2];
        dst[3] = src[3];
    } else {
        // thread pair per node: hf selects k-pair {2hf, 2hf+1}
        const int nl = threadIdx.x >> 1;
        const int hf = threadIdx.x & 1;
        const int node = blockIdx.x * 128 + nl;
        if (node >= N) return;
        float p0x = 0.f, p0y = 0.f, p0z = 0.f, p0w = 0.f;
        float p1x = 0.f, p1y = 0.f, p1z = 0.f, p1w = 0.f;
        const int4* hrow = (const int4*)&hs[nl][0];
#pragma unroll
        for (int i8 = 0; i8 < 8; ++i8) {
            const int4 g = hrow[i8];
            const float2 f0 = i2f2(g.x), f1 = i2f2(g.y), f2v = i2f2(g.z), f3 = i2f2(g.w);
            const float hv[8] = {f0.x, f0.y, f1.x, f1.y, f2v.x, f2v.y, f3.x, f3.y};
#pragma unroll
            for (int j = 0; j < 8; ++j) {
                const int i = i8 * 8 + j;
                const float4 w0 = *(const float4*)&W4s[(hf * 2 + 0) * 256 + i * 4];
                const float4 w1 = *(const float4*)&W4s[(hf * 2 + 1) * 256 + i * 4];
                p0x += hv[j] * w0.x; p0y += hv[j] * w0.y;
                p0z += hv[j] * w0.z; p0w += hv[j] * w0.w;
                p1x += hv[j] * w1.x; p1y += hv[j] * w1.y;
                p1z += hv[j] * w1.z; p1w += hv[j] * w1.w;
            }
        }
        ((float4*)P)[(size_t)(hf * 2 + 0) * N + node] = make_float4(p0x, p0y, p0z, p0w);
        ((float4*)P)[(size_t)(hf * 2 + 1) * N + node] = make_float4(p1x, p1y, p1z, p1w);
    }
}

// Horner step on 4-dim fp32 signals: out[n] = P[n] (+bias) + sum_e norm_e * U[src_e]
template <bool FINAL>
__global__ __launch_bounds__(256) void prop1_add_kernel(const int* __restrict__ off,
                                                        const unsigned int* __restrict__ recs,
                                                        const float* __restrict__ Uin,
                                                        const float* __restrict__ P,
                                                        const float* __restrict__ b,
                                                        float* __restrict__ out, int nNodes) {
    const int n = blockIdx.x * 256 + threadIdx.x;
    if (n >= nNodes) return;
    const float4* __restrict__ u4 = (const float4*)Uin;
    float4 acc = ((const float4*)P)[n];
    if (FINAL) {
        const float4 bv = *(const float4*)b;
        acc.x += bv.x;
        acc.y += bv.y;
        acc.z += bv.z;
        acc.w += bv.w;
    }
    int e = off[n];
    const int e1 = off[n + 1];
    for (; e + 4 <= e1; e += 4) {
        const unsigned int r0 = recs[e + 0];
        const unsigned int r1 = recs[e + 1];
        const unsigned int r2 = recs[e + 2];
        const unsigned int r3 = recs[e + 3];
        const float4 a = u4[r0 >> 15], bb = u4[r1 >> 15];
        const float4 c = u4[r2 >> 15], d = u4[r3 >> 15];
        const float w0 = hbits2f((r0 & 0x7FFFu) << 1);
        const float w1 = hbits2f((r1 & 0x7FFFu) << 1);
        const float w2 = hbits2f((r2 & 0x7FFFu) << 1);
        const float w3 = hbits2f((r3 & 0x7FFFu) << 1);
        acc.x += w0 * a.x + w1 * bb.x + w2 * c.x + w3 * d.x;
        acc.y += w0 * a.y + w1 * bb.y + w2 * c.y + w3 * d.y;
        acc.z += w0 * a.z + w1 * bb.z + w2 * c.z + w3 * d.z;
        acc.w += w0 * a.w + w1 * bb.w + w2 * c.w + w3 * d.w;
    }
    for (; e < e1; ++e) {
        const unsigned int r = recs[e];
        const float ww = hbits2f((r & 0x7FFFu) << 1);
        const float4 hv = u4[r >> 15];
        acc.x += ww * hv.x;
        acc.y += ww * hv.y;
        acc.z += ww * hv.z;
        acc.w += ww * hv.w;
    }
    ((float4*)out)[n] = acc;
}

// ---------------- host ----------------

extern "C" void kernel_launch(void* const* d_in, const int* in_sizes, int n_in,
                              void* d_out, int out_size, void* d_ws, size_t ws_size,
                              hipStream_t stream) {
    const float* x = (const float*)d_in[0];
    const int* ei = (const int*)d_in[1];
    const float* W[5] = {(const float*)d_in[2], (const float*)d_in[4], (const float*)d_in[6],
                         (const float*)d_in[8], (const float*)d_in[10]};
    const float* bb[5] = {(const float*)d_in[3], (const float*)d_in[5], (const float*)d_in[7],
                          (const float*)d_in[9], (const float*)d_in[11]};
    const int E = in_sizes[1] / 2;   // 800000
    const int N = in_sizes[0] / 16;  // 50000
    float* outp = (float*)d_out;

    char* p = (char*)d_ws;
    auto alloc = [&](size_t bytes) {
        char* r = p;
        p += (bytes + 255) & ~size_t(255);
        return r;
    };
    const int nb = (N + 255) / 256;
    int* cnt = (int*)alloc((size_t)N * 4);
    int* off = (int*)alloc((size_t)(N + 1) * 4);
    float* dinv = (float*)alloc((size_t)N * 4);
    int* bsum = (int*)alloc((size_t)nb * 4);
    unsigned short* rank = (unsigned short*)alloc((size_t)E * 2);
    unsigned int* recs = (unsigned int*)alloc((size_t)E * 4);
    __half* xcat = (__half*)alloc((size_t)N * 64 * 2);
    __half* hcatA = (__half*)alloc((size_t)N * 256 * 2);
    __half* hcatB = (__half*)alloc((size_t)N * 256 * 2);
    __half* Bp0 = (__half*)alloc((size_t)512 * 8 * 2);
    __half* Bp1 = (__half*)alloc((size_t)2048 * 8 * 2);
    __half* Bp2 = (__half*)alloc((size_t)2048 * 8 * 2);
    __half* Bp3 = (__half*)alloc((size_t)2048 * 8 * 2);
    float* Pall = (float*)alloc((size_t)4 * N * 4 * 4);  // P_k[n][4], k-major
    float* Ua = (float*)alloc((size_t)N * 4 * 4);
    float* Ub = (float*)alloc((size_t)N * 4 * 4);

    hipMemsetAsync(cnt, 0, (size_t)N * 4, stream);
    const int eb = (E + 255) / 256;
    count_rank_kernel<<<eb, 256, 0, stream>>>(ei + E, cnt, rank, E);
    scan_block_kernel<<<nb, 256, 0, stream>>>(cnt, off, bsum, N);
    scan_apply_kernel<<<nb, 256, 0, stream>>>(off, bsum, N, E);
    const int prep_total = 3 * N + 512 + 3 * 2048;
    prep_kernel<<<(prep_total + 255) / 256, 256, 0, stream>>>(
        cnt, dinv, x, xcat, W[0], W[1], W[2], W[3], Bp0, Bp1, Bp2, Bp3, N);
    scatter_kernel<<<eb, 256, 0, stream>>>(ei, ei + E, off, rank, dinv, recs, E);

    const int gh2 = (N * 2 + 255) / 256;   // DQ=2 hop grid
    const int gh8 = (N * 8 + 255) / 256;   // DQ=8 hop grid
    const int gm = (N + 127) / 128;        // MFMA gemm grid
    const int p1 = (N + 255) / 256;

    // Layer 0: hops fill xcat col-slices (16-dim); MFMA GEMM K=64 -> hcatA cols 0..63
    gatherh_kernel<2, 8><<<gh2, 256, 0, stream>>>(off, recs, xcat + 0, xcat + 16, N);
    gatherh_kernel<2, 8><<<gh2, 256, 0, stream>>>(off, recs, xcat + 16, xcat + 32, N);
    gatherh_kernel<2, 8><<<gh2, 256, 0, stream>>>(off, recs, xcat + 32, xcat + 48, N);
    gemmcat_mfma<64, false><<<gm, 256, 0, stream>>>(xcat, Bp0, bb[0], hcatA, nullptr,
                                                    nullptr, N);

    // Layers 1-2: hops + MFMA GEMM K=256 (write next hcat)
    __half* cur = hcatA;
    __half* nxt = hcatB;
    const __half* Bps[4] = {nullptr, Bp1, Bp2, Bp3};
    for (int l = 1; l <= 2; ++l) {
        gatherh_kernel<8, 32><<<gh8, 256, 0, stream>>>(off, recs, cur + 0, cur + 64, N);
        gatherh_kernel<8, 32><<<gh8, 256, 0, stream>>>(off, recs, cur + 64, cur + 128, N);
        gatherh_kernel<8, 32><<<gh8, 256, 0, stream>>>(off, recs, cur + 128, cur + 192, N);
        gemmcat_mfma<256, false><<<gm, 256, 0, stream>>>(cur, Bps[l], bb[l], nxt, nullptr,
                                                         nullptr, N);
        __half* t = cur;
        cur = nxt;
        nxt = t;
    }

    // Layer 3: hops + MFMA GEMM with fused proj4 epilogue (no hcat write)
    gatherh_kernel<8, 32><<<gh8, 256, 0, stream>>>(off, recs, cur + 0, cur + 64, N);
    gatherh_kernel<8, 32><<<gh8, 256, 0, stream>>>(off, recs, cur + 64, cur + 128, N);
    gatherh_kernel<8, 32><<<gh8, 256, 0, stream>>>(off, recs, cur + 128, cur + 192, N);
    gemmcat_mfma<256, true><<<gm, 256, 0, stream>>>(cur, Bp3, bb[3], nullptr, W[4], Pall, N);

    // Layer 4 Horner on 4-dim fp32 signals: out = P0 + b + A(P1 + A(P2 + A*P3))
    float* P0 = Pall + (size_t)0 * N * 4;
    float* P1 = Pall + (size_t)1 * N * 4;
    float* P2 = Pall + (size_t)2 * N * 4;
    float* P3 = Pall + (size_t)3 * N * 4;
    prop1_add_kernel<false><<<p1, 256, 0, stream>>>(off, recs, P3, P2, nullptr, Ua, N);
    prop1_add_kernel<false><<<p1, 256, 0, stream>>>(off, recs, Ua, P1, nullptr, Ub, N);
    prop1_add_kernel<true><<<p1, 256, 0, stream>>>(off, recs, Ub, P0, bb[4], outp, N);
}